// Round 4
// baseline (316.578 us; speedup 1.0000x reference)
//
#include <hip/hip_runtime.h>
#include <math.h>

#define NSITE 100
#define NOCC  50
#define DIM   128
#define KDET  4
#define NTAB  400                         // K*(N_UP+N_DOWN)
#define TP_FLOATS ((4 + 144) * NTAB)      // T then P' in ws

// ---------------------------------------------------------------------------
// R18: GEMM collapsed into T[4][400]/P'[144][400] table adds.
// R19: pipelined pivot + SALU parity: 197 -> 170us (1 wave/det, unrolled).
// R20: bigger reg budget: no help (spills persisted). 181us.
// R21: 2 waves/det: spills GONE (VGPR 28, WRITE=output only) but 198us.
//      Across all three: VALUBusy ~88% yet measured busy cycles ~3x the
//      static VALU count. Common factor: 40-50KB straight-line LU body >>
//      I$; 16 staggered waves thrash instruction fetch (invisible in
//      counters -- code refetch hits L2, not HBM).
// R22 (this round): ROLLED LU loop (~1KB body). Register shift-down keeps
//      the current column in q0: update IS the shift
//      (q_L = fma(-mult, pc(q_{L+1}), q_{L+1})), all names static, body
//      identical each iteration. Dead high regs pinned to 0. Live-column
//      math is op-identical to R19 -> absmax 0. 2x fma work on dead zeros,
//      but I$-resident; if the 3x fetch tax is real this nets ~2x faster.
// ---------------------------------------------------------------------------

// Wave64 max-reduction via DPP (VALU-only). Lane 63 ends with global max.
__device__ __forceinline__ unsigned dpp_max64_to_lane63(unsigned x) {
  unsigned t;
  t = (unsigned)__builtin_amdgcn_update_dpp((int)x, (int)x, 0x111, 0xf, 0xf, false);
  x = x > t ? x : t;
  t = (unsigned)__builtin_amdgcn_update_dpp((int)x, (int)x, 0x112, 0xf, 0xf, false);
  x = x > t ? x : t;
  t = (unsigned)__builtin_amdgcn_update_dpp((int)x, (int)x, 0x114, 0xf, 0xf, false);
  x = x > t ? x : t;
  t = (unsigned)__builtin_amdgcn_update_dpp((int)x, (int)x, 0x118, 0xf, 0xf, false);
  x = x > t ? x : t;
  t = (unsigned)__builtin_amdgcn_update_dpp((int)x, (int)x, 0x142, 0xa, 0xf, false);
  x = x > t ? x : t;
  t = (unsigned)__builtin_amdgcn_update_dpp((int)x, (int)x, 0x143, 0xc, 0xf, false);
  x = x > t ? x : t;
  return x;
}

#define REPB(X) X(0) X(1) X(2) X(3) X(4) X(5) X(6) X(7) X(8) X(9) \
  X(10) X(11) X(12) X(13) X(14) X(15) X(16) X(17) X(18) X(19) \
  X(20) X(21) X(22) X(23) X(24) X(25) X(26) X(27) X(28) X(29) \
  X(30) X(31) X(32) X(33) X(34) X(35) X(36) X(37) X(38) X(39) \
  X(40) X(41) X(42) X(43) X(44) X(45) X(46) X(47) X(48) X(49)

// shift-updates for L = 1..48 (L <- L+1); L=0 handled separately (pipelining)
#define REPU(X) \
  X(1,2) X(2,3) X(3,4) X(4,5) X(5,6) X(6,7) X(7,8) X(8,9) X(9,10) \
  X(10,11) X(11,12) X(12,13) X(13,14) X(14,15) X(15,16) X(16,17) X(17,18) \
  X(18,19) X(19,20) X(20,21) X(21,22) X(22,23) X(23,24) X(24,25) X(25,26) \
  X(26,27) X(27,28) X(28,29) X(29,30) X(30,31) X(31,32) X(32,33) X(33,34) \
  X(34,35) X(35,36) X(36,37) X(37,38) X(38,39) X(39,40) X(40,41) X(41,42) \
  X(42,43) X(43,44) X(44,45) X(45,46) X(46,47) X(47,48) X(48,49)

// ---- Precompute: T[c][j] = tok[c].W_j ; P'[s][j] = pos[s].W_j + b_j ------
__global__ __launch_bounds__(256) void tp_kernel(
    const float* __restrict__ tok, const float* __restrict__ pos,
    const float* __restrict__ W,   const float* __restrict__ bvec,
    float* __restrict__ T, float* __restrict__ P)
{
  const int gid = blockIdx.x * 256 + threadIdx.x;
  if (gid >= 148 * NTAB) return;
  const int row = gid / NTAB;
  const int col = gid - row * NTAB;
  const float4* h4 = (const float4*)((row < 4) ? (tok + (size_t)row * DIM)
                                               : (pos + (size_t)(row - 4) * DIM));
  const float4* w4 = (const float4*)(W + (size_t)col * DIM);
  float acc = 0.0f;
  #pragma unroll
  for (int i = 0; i < DIM / 4; ++i) {
    float4 a = h4[i], b = w4[i];
    acc = fmaf(a.x, b.x, acc);
    acc = fmaf(a.y, b.y, acc);
    acc = fmaf(a.z, b.z, acc);
    acc = fmaf(a.w, b.w, acc);
  }
  if (row < 4) T[(size_t)row * NTAB + col] = acc;
  else         P[(size_t)(row - 4) * NTAB + col] = acc + bvec[col];
}

// One block per (batch, spin). Wave w handles determinant k=w.
// Lane r owns row r of phi; register q_L holds column (J+L) at LU step J.
__global__ __launch_bounds__(256)
__attribute__((amdgpu_waves_per_eu(6)))
void det_kernel(
    const int*   __restrict__ configs,   // (B,100) int32
    const float* __restrict__ T,         // (4,400)
    const float* __restrict__ P,         // (144,400)  includes bias
    double*      __restrict__ dets)      // (B,2,4,2)  {logdet, sign}
{
  const int b    = blockIdx.x;
  const int spin = blockIdx.y;

  __shared__ int cfg[NSITE];
  __shared__ int idx[NOCC];
  __shared__ unsigned long long omask[2];

  const int tid = threadIdx.x;

  // ---- wave-parallel occupied-index build (ballot + prefix popcount) ----
  bool occv = false;
  if (tid < NSITE) {
    const int c = configs[(size_t)b * NSITE + tid];
    cfg[tid] = c;
    occv = (spin == 0) ? (c == 1 || c == 3) : (c == 2 || c == 3);
  }
  const unsigned long long bal = __ballot(occv);
  if ((tid & 63) == 0 && tid < 128) omask[tid >> 6] = bal;
  __syncthreads();
  if (tid < NSITE) {
    const unsigned long long m0 = omask[0], m1 = omask[1];
    const int mtot = __popcll(m0) + __popcll(m1);
    const int need = (mtot < NOCC) ? (NOCC - mtot) : 0;
    int pocc;
    if (tid >= 64) pocc = __popcll(m0) + __popcll(m1 & ((1ull << (tid - 64)) - 1ull));
    else           pocc = __popcll(m0 & ((1ull << tid) - 1ull));
    const int punocc = tid - pocc;
    const bool sel = occv ? (pocc < NOCC) : (punocc < need);
    const int  poscap = (pocc  < NOCC) ? pocc  : NOCC;
    const int  pfill  = (punocc < need) ? punocc : need;
    if (sel) idx[poscap + pfill] = tid;
  }
  __syncthreads();

  const int lane = tid & 63;
  const int wave = tid >> 6;
  const int wave_u  = __builtin_amdgcn_readfirstlane(wave);
  const int colbase = spin * 200 + wave_u * 50;          // uniform

  const bool act  = (lane < NOCC);
  const int  site = idx[act ? lane : 0];
  const int  cc0  = cfg[site];
  // colbase is a multiple of 50 -> byte offset multiple of 200 -> 8-aligned
  const float2* T2 = (const float2*)(T + (size_t)cc0  * NTAB + colbase);
  const float2* P2 = (const float2*)(P + (size_t)site * NTAB + colbase);

  // ---- assemble phi row: q_j = T[c][cb+j] + P'[site][cb+j] ----
  #define DECLQ(i) float q##i;
  REPB(DECLQ)
  #undef DECLQ
  #define LQ(i0, i1) { float2 a = T2[(i0) / 2], c = P2[(i0) / 2]; \
      q##i0 = a.x + c.x; q##i1 = a.y + c.y; }
  LQ(0, 1)  LQ(2, 3)  LQ(4, 5)  LQ(6, 7)  LQ(8, 9)  LQ(10, 11)
  __builtin_amdgcn_sched_barrier(0);
  LQ(12, 13) LQ(14, 15) LQ(16, 17) LQ(18, 19) LQ(20, 21) LQ(22, 23)
  __builtin_amdgcn_sched_barrier(0);
  LQ(24, 25) LQ(26, 27) LQ(28, 29) LQ(30, 31) LQ(32, 33) LQ(34, 35)
  __builtin_amdgcn_sched_barrier(0);
  LQ(36, 37) LQ(38, 39) LQ(40, 41) LQ(42, 43) LQ(44, 45) LQ(46, 47)
  __builtin_amdgcn_sched_barrier(0);
  LQ(48, 49)
  #undef LQ

  // zero inactive lanes so they never win the pivot and updates stay benign
  #define ZEROQ(i) q##i = act ? q##i : 0.0f;
  REPB(ZEROQ)
  #undef ZEROQ

  __builtin_amdgcn_sched_barrier(0);

  // ---- LU (fp32), rolled loop, register shift-down ----------------------
  unsigned aliveq = act ? 0xFFFFFFFFu : 0u;   // per-lane alive mask
  float    mant_prod = 1.0f;                  // pivot mantissa product < 2^50
  int      esum = 0;
  unsigned sgnx = 0u;
  unsigned long long chosen = 0ull;
  int      invsum = 0;
  const unsigned lu = (unsigned)lane;

  unsigned keyv;
  int   p;    // current pivot lane (uniform)
  float rp;   // reciprocal of current pivot (uniform value)

  // consume keyv -> p, piv(from q0), rp; SALU accounting; retire lane p
  #define PIVFIN0 { \
    p = __builtin_amdgcn_readlane((int)keyv, 63) & 63; \
    const unsigned pb = (unsigned)__builtin_amdgcn_readlane( \
        __float_as_int(q0), p); \
    esum += (int)((pb >> 23) & 0xFFu) - 127; \
    sgnx ^= (pb & 0x80000000u); \
    mant_prod *= __uint_as_float((pb & 0x007FFFFFu) | 0x3F800000u); \
    invsum += __popcll(chosen >> (p + 1)); \
    chosen |= 1ull << (unsigned)p; \
    aliveq = ((unsigned)lane == (unsigned)p) ? 0u : aliveq; \
    const float piv = __uint_as_float(pb); \
    float r0 = __builtin_amdgcn_rcpf(piv); \
    r0 = fmaf(fmaf(-piv, r0, 1.0f), r0, r0); \
    rp = ((pb & 0x7FFFFFFFu) != 0u) ? r0 : 0.0f; }

  // prologue: pivot of column 0 (in q0)
  keyv = ((__float_as_uint(q0) & 0x7FFFFFC0u) | lu) & aliveq;
  keyv = dpp_max64_to_lane63(keyv);
  PIVFIN0

  #define USH(L, L1) { const float pc = __int_as_float( \
      __builtin_amdgcn_readlane(__float_as_int(q##L1), p)); \
      q##L = fmaf(-mult, pc, q##L1); }

  // Each iteration J: eliminate col J (mult from q0), shift regs down,
  // compute + account pivot of col J+1 (lands in new q0). DPP chain for
  // the next pivot is issued right after the L=0 update so the 48
  // trailing updates hide its latency. q49 pinned to 0 = dead region.
  #pragma unroll 1
  for (int J = 0; J < 49; ++J) {
    const float mult = __uint_as_float(__float_as_uint(q0 * rp) & aliveq);
    USH(0, 1)                                   // new current column
    keyv = ((__float_as_uint(q0) & 0x7FFFFFC0u) | lu) & aliveq;
    keyv = dpp_max64_to_lane63(keyv);
    REPU(USH)                                   // trailing 48 shifts
    q49 = 0.0f;
    PIVFIN0                                     // pivot/accounting col J+1
  }
  #undef USH
  #undef PIVFIN0

  const double logdet =
      log((double)mant_prod) + (double)esum * 0.6931471805599453;
  const int sgn = (((sgnx >> 31) + (unsigned)invsum) & 1u) ? -1 : 1;

  if (lane == 0) {
    size_t o = (((size_t)b * 2 + spin) * KDET + wave) * 2;
    dets[o]     = logdet;
    dets[o + 1] = (double)sgn;
  }
}

// PLANAR complex64 output: out[0..B) = log_abs (real), out[B..2B) = phase (imag)
__global__ __launch_bounds__(256) void combine_kernel(
    const double* __restrict__ dets, float* __restrict__ out, int B)
{
  int b = blockIdx.x * blockDim.x + threadIdx.x;
  if (b >= B) return;
  const double* du = dets + ((size_t)b * 2 + 0) * KDET * 2;
  const double* dd = dets + ((size_t)b * 2 + 1) * KDET * 2;
  double t[KDET], s[KDET], m = -1e300;
  #pragma unroll
  for (int k = 0; k < KDET; ++k) {
    t[k] = du[2 * k] + dd[2 * k];
    s[k] = du[2 * k + 1] * dd[2 * k + 1];
    if (t[k] > m) m = t[k];
  }
  double sum = 0.0;
  #pragma unroll
  for (int k = 0; k < KDET; ++k) {
    if (t[k] > -1e290) sum += s[k] * exp(t[k] - m);
  }
  double p  = (m > -1e290) ? exp(m) * fabs(sum) : 0.0;
  double la = log(p + 1e-30);                    // reproduce ref clamp exactly
  float phase = (sum >= 0.0) ? 0.0f : 3.14159265358979f;
  out[b]     = (float)la;
  out[B + b] = phase;
}

extern "C" void kernel_launch(void* const* d_in, const int* in_sizes, int n_in,
                              void* d_out, int out_size, void* d_ws, size_t ws_size,
                              hipStream_t stream) {
  const int*   configs = (const int*)  d_in[0];
  const float* tok     = (const float*)d_in[1];
  const float* pos     = (const float*)d_in[2];
  const float* W       = (const float*)d_in[3];
  const float* bv      = (const float*)d_in[4];

  float*  wsf  = (float*)d_ws;
  float*  T    = wsf;                       // 4*400 floats
  float*  P    = wsf + 4 * NTAB;            // 144*400 floats
  double* dets = (double*)(wsf + TP_FLOATS);  // 236800B offset, 8-aligned
  const int B = in_sizes[0] / NSITE;        // total ws: ~499KB

  tp_kernel<<<(148 * NTAB + 255) / 256, 256, 0, stream>>>(tok, pos, W, bv, T, P);
  dim3 grid(B, 2);
  det_kernel<<<grid, 256, 0, stream>>>(configs, T, P, dets);
  combine_kernel<<<(B + 255) / 256, 256, 0, stream>>>(dets, (float*)d_out, B);
}

// Round 5
// 224.552 us; speedup vs baseline: 1.4098x; 1.4098x over previous
//
#include <hip/hip_runtime.h>
#include <math.h>

#define NSITE 100
#define NOCC  50
#define DIM   128
#define KDET  4
#define NTAB  400                         // K*(N_UP+N_DOWN)
#define TP_FLOATS ((4 + 144) * NTAB)      // T then P' in ws

// ---------------------------------------------------------------------------
// R18: GEMM collapsed into T[4][400]/P'[144][400] table adds.
// R19: 1 wave/det, pipelined pivot, SALU parity: 170us BUT VGPR spills
//      (50 live cols never fit; WRITE_SIZE 13.5MB scratch).
// R20: bigger budget: spills persist, 181us.
// R21: 2 waves/det: clean alloc (VGPR 28) but 198us -- 50 barriers/det +
//      LDS round-trip + redundant accounting ate the gain.
// R22: rolled shift-loop: 50 loop PHIs re-spilled (13.4MB), 261us.
// Ledger: spilling variants show ~3.3x VALU inflation (spill shuttle);
// clean R21 shows ~2.4x (barrier structure). No universal tax.
// R23 (this round): TWO-PANEL LU, 1 wave/det, no barriers, no spills.
//   Phase 1: factor cols 0..24 in 25 regs; per step write masked
//     multiplier vector to per-wave LDS stash (6.4KB), pack pivot lane
//     into 3 uint64 SGPRs; col reg dies after its step.
//   Phase 2: load cols 25..49 (reuse dead regs); replay steps 0..24
//     (mult = 1 LDS read/step, pivot row via readlane).
//   Phase 3: factor steps 25..49 in-register.
// Same fma sequence per element as R19/R21 -> bit-identical, absmax 0.
// Peak live ~35-40 VGPR. LDS 26.2KB/block -> 6 blocks/CU (~6 waves/SIMD).
// ---------------------------------------------------------------------------

// Wave64 max-reduction via DPP (VALU-only). Lane 63 ends with global max.
__device__ __forceinline__ unsigned dpp_max64_to_lane63(unsigned x) {
  unsigned t;
  t = (unsigned)__builtin_amdgcn_update_dpp((int)x, (int)x, 0x111, 0xf, 0xf, false);
  x = x > t ? x : t;
  t = (unsigned)__builtin_amdgcn_update_dpp((int)x, (int)x, 0x112, 0xf, 0xf, false);
  x = x > t ? x : t;
  t = (unsigned)__builtin_amdgcn_update_dpp((int)x, (int)x, 0x114, 0xf, 0xf, false);
  x = x > t ? x : t;
  t = (unsigned)__builtin_amdgcn_update_dpp((int)x, (int)x, 0x118, 0xf, 0xf, false);
  x = x > t ? x : t;
  t = (unsigned)__builtin_amdgcn_update_dpp((int)x, (int)x, 0x142, 0xa, 0xf, false);
  x = x > t ? x : t;
  t = (unsigned)__builtin_amdgcn_update_dpp((int)x, (int)x, 0x143, 0xc, 0xf, false);
  x = x > t ? x : t;
  return x;
}

// 25-wide repeat
#define REPC(X) X(0) X(1) X(2) X(3) X(4) X(5) X(6) X(7) X(8) X(9) \
  X(10) X(11) X(12) X(13) X(14) X(15) X(16) X(17) X(18) X(19) \
  X(20) X(21) X(22) X(23) X(24)

// ---- Precompute: T[c][j] = tok[c].W_j ; P'[s][j] = pos[s].W_j + b_j ------
__global__ __launch_bounds__(256) void tp_kernel(
    const float* __restrict__ tok, const float* __restrict__ pos,
    const float* __restrict__ W,   const float* __restrict__ bvec,
    float* __restrict__ T, float* __restrict__ P)
{
  const int gid = blockIdx.x * 256 + threadIdx.x;
  if (gid >= 148 * NTAB) return;
  const int row = gid / NTAB;
  const int col = gid - row * NTAB;
  const float4* h4 = (const float4*)((row < 4) ? (tok + (size_t)row * DIM)
                                               : (pos + (size_t)(row - 4) * DIM));
  const float4* w4 = (const float4*)(W + (size_t)col * DIM);
  float acc = 0.0f;
  #pragma unroll
  for (int i = 0; i < DIM / 4; ++i) {
    float4 a = h4[i], b = w4[i];
    acc = fmaf(a.x, b.x, acc);
    acc = fmaf(a.y, b.y, acc);
    acc = fmaf(a.z, b.z, acc);
    acc = fmaf(a.w, b.w, acc);
  }
  if (row < 4) T[(size_t)row * NTAB + col] = acc;
  else         P[(size_t)(row - 4) * NTAB + col] = acc + bvec[col];
}

// One block per (batch, spin). Wave w handles determinant k=w.
// Lane r owns row r of phi. Two-panel LU; see header comment.
__global__ __launch_bounds__(256)
__attribute__((amdgpu_waves_per_eu(6)))
void det_kernel(
    const int*   __restrict__ configs,   // (B,100) int32
    const float* __restrict__ T,         // (4,400)
    const float* __restrict__ P,         // (144,400)  includes bias
    double*      __restrict__ dets)      // (B,2,4,2)  {logdet, sign}
{
  const int b    = blockIdx.x;
  const int spin = blockIdx.y;

  __shared__ int cfg[NSITE];
  __shared__ int idx[NOCC];
  __shared__ unsigned long long omask[2];
  __shared__ float stash[4][25][64];     // per-wave multiplier stash

  const int tid = threadIdx.x;

  // ---- wave-parallel occupied-index build (ballot + prefix popcount) ----
  bool occv = false;
  if (tid < NSITE) {
    const int c = configs[(size_t)b * NSITE + tid];
    cfg[tid] = c;
    occv = (spin == 0) ? (c == 1 || c == 3) : (c == 2 || c == 3);
  }
  const unsigned long long bal = __ballot(occv);
  if ((tid & 63) == 0 && tid < 128) omask[tid >> 6] = bal;
  __syncthreads();
  if (tid < NSITE) {
    const unsigned long long m0 = omask[0], m1 = omask[1];
    const int mtot = __popcll(m0) + __popcll(m1);
    const int need = (mtot < NOCC) ? (NOCC - mtot) : 0;
    int pocc;
    if (tid >= 64) pocc = __popcll(m0) + __popcll(m1 & ((1ull << (tid - 64)) - 1ull));
    else           pocc = __popcll(m0 & ((1ull << tid) - 1ull));
    const int punocc = tid - pocc;
    const bool sel = occv ? (pocc < NOCC) : (punocc < need);
    const int  poscap = (pocc  < NOCC) ? pocc  : NOCC;
    const int  pfill  = (punocc < need) ? punocc : need;
    if (sel) idx[poscap + pfill] = tid;
  }
  __syncthreads();

  const int lane = tid & 63;
  const int wave = tid >> 6;
  const int wave_u  = __builtin_amdgcn_readfirstlane(wave);
  const int colbase = spin * 200 + wave_u * 50;          // uniform

  const bool act  = (lane < NOCC);
  const int  site = idx[act ? lane : 0];
  const int  cc0  = cfg[site];
  const float* Trow = T + (size_t)cc0  * NTAB + colbase;
  const float* Prow = P + (size_t)site * NTAB + colbase;
  // colbase multiple of 50 -> byte offset multiple of 200 -> 8-aligned
  const float2* T2 = (const float2*)Trow;
  const float2* P2 = (const float2*)Prow;

  // ================= phase 1: cols 0..24 in c0..c24 =================
  #define DECLC(i) float c##i;
  REPC(DECLC)
  #undef DECLC
  #define LQ(i0, i1) { float2 a = T2[(i0) / 2], d = P2[(i0) / 2]; \
      c##i0 = a.x + d.x; c##i1 = a.y + d.y; }
  LQ(0, 1)  LQ(2, 3)  LQ(4, 5)  LQ(6, 7)  LQ(8, 9)  LQ(10, 11)
  LQ(12, 13) LQ(14, 15) LQ(16, 17) LQ(18, 19) LQ(20, 21) LQ(22, 23)
  #undef LQ
  c24 = Trow[24] + Prow[24];
  #define ZC(i) c##i = act ? c##i : 0.0f;
  REPC(ZC)
  #undef ZC

  unsigned aliveq = act ? 0xFFFFFFFFu : 0u;   // per-lane alive mask
  float    mant_prod = 1.0f;                  // pivot mantissa product < 2^50
  int      esum = 0;
  unsigned sgnx = 0u;
  unsigned long long chosen = 0ull;
  int      invsum = 0;
  const unsigned lu = (unsigned)lane;
  unsigned long long pp[3] = {0ull, 0ull, 0ull};  // packed pivot lanes, 6b ea

  // update chains, c family: UCF_N applies UC to regs N..24
  #define UC(L) { const float pc = __int_as_float( \
      __builtin_amdgcn_readlane(__float_as_int(c##L), p)); \
      c##L = fmaf(-mult, pc, c##L); }
  #define UCF_25
  #define UCF_24 UC(24)
  #define UCF_23 UC(23) UCF_24
  #define UCF_22 UC(22) UCF_23
  #define UCF_21 UC(21) UCF_22
  #define UCF_20 UC(20) UCF_21
  #define UCF_19 UC(19) UCF_20
  #define UCF_18 UC(18) UCF_19
  #define UCF_17 UC(17) UCF_18
  #define UCF_16 UC(16) UCF_17
  #define UCF_15 UC(15) UCF_16
  #define UCF_14 UC(14) UCF_15
  #define UCF_13 UC(13) UCF_14
  #define UCF_12 UC(12) UCF_13
  #define UCF_11 UC(11) UCF_12
  #define UCF_10 UC(10) UCF_11
  #define UCF_9  UC(9)  UCF_10
  #define UCF_8  UC(8)  UCF_9
  #define UCF_7  UC(7)  UCF_8
  #define UCF_6  UC(6)  UCF_7
  #define UCF_5  UC(5)  UCF_6
  #define UCF_4  UC(4)  UCF_5
  #define UCF_3  UC(3)  UCF_4
  #define UCF_2  UC(2)  UCF_3
  #define UCF_1  UC(1)  UCF_2

  // Step J (global step J, 0..24): pivot, account, stash mult, update tail.
  #define P1STEP(J, N) { \
    unsigned key = ((__float_as_uint(c##J) & 0x7FFFFFC0u) | lu) & aliveq; \
    key = dpp_max64_to_lane63(key); \
    const int p = __builtin_amdgcn_readlane((int)key, 63) & 63; \
    const unsigned pb = (unsigned)__builtin_amdgcn_readlane( \
        __float_as_int(c##J), p); \
    esum += (int)((pb >> 23) & 0xFFu) - 127; \
    sgnx ^= (pb & 0x80000000u); \
    mant_prod *= __uint_as_float((pb & 0x007FFFFFu) | 0x3F800000u); \
    invsum += __popcll(chosen >> (p + 1)); \
    chosen |= 1ull << (unsigned)p; \
    aliveq = (lane == p) ? 0u : aliveq; \
    pp[(J) / 10] |= ((unsigned long long)(unsigned)p) << (6 * ((J) % 10)); \
    const float piv = __uint_as_float(pb); \
    float r0 = __builtin_amdgcn_rcpf(piv); \
    r0 = fmaf(fmaf(-piv, r0, 1.0f), r0, r0); \
    const float rp = ((pb & 0x7FFFFFFFu) != 0u) ? r0 : 0.0f; \
    const float mult = __uint_as_float(__float_as_uint(c##J * rp) & aliveq); \
    stash[wave_u][(J)][lane] = mult; \
    UCF_##N \
  }

  P1STEP(0,1)   P1STEP(1,2)   P1STEP(2,3)   P1STEP(3,4)   P1STEP(4,5)
  P1STEP(5,6)   P1STEP(6,7)   P1STEP(7,8)   P1STEP(8,9)   P1STEP(9,10)
  P1STEP(10,11) P1STEP(11,12) P1STEP(12,13) P1STEP(13,14) P1STEP(14,15)
  P1STEP(15,16) P1STEP(16,17) P1STEP(17,18) P1STEP(18,19) P1STEP(19,20)
  P1STEP(20,21) P1STEP(21,22) P1STEP(22,23) P1STEP(23,24) P1STEP(24,25)
  #undef P1STEP

  // ================= phase 2: cols 25..49, replay steps 0..24 ============
  #define DECLT(i) float t##i;
  REPC(DECLT)
  #undef DECLT
  #define LT(i) t##i = Trow[25 + (i)] + Prow[25 + (i)];
  REPC(LT)
  #undef LT
  #define ZT(i) t##i = act ? t##i : 0.0f;
  REPC(ZT)
  #undef ZT

  #define UT(L) { const float pc = __int_as_float( \
      __builtin_amdgcn_readlane(__float_as_int(t##L), p)); \
      t##L = fmaf(-mult, pc, t##L); }

  // replay step J on all 25 trailing cols (mult from stash, p from pack)
  #define P2J(J) { \
    const int p = (int)((pp[(J) / 10] >> (6 * ((J) % 10))) & 63ull); \
    const float mult = stash[wave_u][(J)][lane]; \
    REPC(UT) \
  }
  P2J(0)  P2J(1)  P2J(2)  P2J(3)  P2J(4)  P2J(5)  P2J(6)  P2J(7)
  P2J(8)  P2J(9)  P2J(10) P2J(11) P2J(12) P2J(13) P2J(14) P2J(15)
  P2J(16) P2J(17) P2J(18) P2J(19) P2J(20) P2J(21) P2J(22) P2J(23)
  P2J(24)
  #undef P2J

  // ================= phase 3: factor steps 25..49 on t0..t24 =============
  #define UTF_25
  #define UTF_24 UT(24)
  #define UTF_23 UT(23) UTF_24
  #define UTF_22 UT(22) UTF_23
  #define UTF_21 UT(21) UTF_22
  #define UTF_20 UT(20) UTF_21
  #define UTF_19 UT(19) UTF_20
  #define UTF_18 UT(18) UTF_19
  #define UTF_17 UT(17) UTF_18
  #define UTF_16 UT(16) UTF_17
  #define UTF_15 UT(15) UTF_16
  #define UTF_14 UT(14) UTF_15
  #define UTF_13 UT(13) UTF_14
  #define UTF_12 UT(12) UTF_13
  #define UTF_11 UT(11) UTF_12
  #define UTF_10 UT(10) UTF_11
  #define UTF_9  UT(9)  UTF_10
  #define UTF_8  UT(8)  UTF_9
  #define UTF_7  UT(7)  UTF_8
  #define UTF_6  UT(6)  UTF_7
  #define UTF_5  UT(5)  UTF_6
  #define UTF_4  UT(4)  UTF_5
  #define UTF_3  UT(3)  UTF_4
  #define UTF_2  UT(2)  UTF_3
  #define UTF_1  UT(1)  UTF_2

  #define P3STEP(L, N) { \
    unsigned key = ((__float_as_uint(t##L) & 0x7FFFFFC0u) | lu) & aliveq; \
    key = dpp_max64_to_lane63(key); \
    const int p = __builtin_amdgcn_readlane((int)key, 63) & 63; \
    const unsigned pb = (unsigned)__builtin_amdgcn_readlane( \
        __float_as_int(t##L), p); \
    esum += (int)((pb >> 23) & 0xFFu) - 127; \
    sgnx ^= (pb & 0x80000000u); \
    mant_prod *= __uint_as_float((pb & 0x007FFFFFu) | 0x3F800000u); \
    invsum += __popcll(chosen >> (p + 1)); \
    chosen |= 1ull << (unsigned)p; \
    aliveq = (lane == p) ? 0u : aliveq; \
    const float piv = __uint_as_float(pb); \
    float r0 = __builtin_amdgcn_rcpf(piv); \
    r0 = fmaf(fmaf(-piv, r0, 1.0f), r0, r0); \
    const float rp = ((pb & 0x7FFFFFFFu) != 0u) ? r0 : 0.0f; \
    const float mult = __uint_as_float(__float_as_uint(t##L * rp) & aliveq); \
    UTF_##N \
  }

  P3STEP(0,1)   P3STEP(1,2)   P3STEP(2,3)   P3STEP(3,4)   P3STEP(4,5)
  P3STEP(5,6)   P3STEP(6,7)   P3STEP(7,8)   P3STEP(8,9)   P3STEP(9,10)
  P3STEP(10,11) P3STEP(11,12) P3STEP(12,13) P3STEP(13,14) P3STEP(14,15)
  P3STEP(15,16) P3STEP(16,17) P3STEP(17,18) P3STEP(18,19) P3STEP(19,20)
  P3STEP(20,21) P3STEP(21,22) P3STEP(22,23) P3STEP(23,24) P3STEP(24,25)
  #undef P3STEP
  #undef UT
  #undef UC

  const double logdet =
      log((double)mant_prod) + (double)esum * 0.6931471805599453;
  const int sgn = (((sgnx >> 31) + (unsigned)invsum) & 1u) ? -1 : 1;

  if (lane == 0) {
    size_t o = (((size_t)b * 2 + spin) * KDET + wave) * 2;
    dets[o]     = logdet;
    dets[o + 1] = (double)sgn;
  }
}

// PLANAR complex64 output: out[0..B) = log_abs (real), out[B..2B) = phase (imag)
__global__ __launch_bounds__(256) void combine_kernel(
    const double* __restrict__ dets, float* __restrict__ out, int B)
{
  int b = blockIdx.x * blockDim.x + threadIdx.x;
  if (b >= B) return;
  const double* du = dets + ((size_t)b * 2 + 0) * KDET * 2;
  const double* dd = dets + ((size_t)b * 2 + 1) * KDET * 2;
  double t[KDET], s[KDET], m = -1e300;
  #pragma unroll
  for (int k = 0; k < KDET; ++k) {
    t[k] = du[2 * k] + dd[2 * k];
    s[k] = du[2 * k + 1] * dd[2 * k + 1];
    if (t[k] > m) m = t[k];
  }
  double sum = 0.0;
  #pragma unroll
  for (int k = 0; k < KDET; ++k) {
    if (t[k] > -1e290) sum += s[k] * exp(t[k] - m);
  }
  double p  = (m > -1e290) ? exp(m) * fabs(sum) : 0.0;
  double la = log(p + 1e-30);                    // reproduce ref clamp exactly
  float phase = (sum >= 0.0) ? 0.0f : 3.14159265358979f;
  out[b]     = (float)la;
  out[B + b] = phase;
}

extern "C" void kernel_launch(void* const* d_in, const int* in_sizes, int n_in,
                              void* d_out, int out_size, void* d_ws, size_t ws_size,
                              hipStream_t stream) {
  const int*   configs = (const int*)  d_in[0];
  const float* tok     = (const float*)d_in[1];
  const float* pos     = (const float*)d_in[2];
  const float* W       = (const float*)d_in[3];
  const float* bv      = (const float*)d_in[4];

  float*  wsf  = (float*)d_ws;
  float*  T    = wsf;                       // 4*400 floats
  float*  P    = wsf + 4 * NTAB;            // 144*400 floats
  double* dets = (double*)(wsf + TP_FLOATS);  // 236800B offset, 8-aligned
  const int B = in_sizes[0] / NSITE;        // total ws: ~499KB

  tp_kernel<<<(148 * NTAB + 255) / 256, 256, 0, stream>>>(tok, pos, W, bv, T, P);
  dim3 grid(B, 2);
  det_kernel<<<grid, 256, 0, stream>>>(configs, T, P, dets);
  combine_kernel<<<(B + 255) / 256, 256, 0, stream>>>(dets, (float*)d_out, B);
}

// Round 7
// 195.080 us; speedup vs baseline: 1.6228x; 1.1511x over previous
//
#include <hip/hip_runtime.h>
#include <math.h>

#define NSITE 100
#define NOCC  50
#define DIM   128
#define KDET  4
#define NTAB  400                         // K*(N_UP+N_DOWN)
#define TP_FLOATS ((4 + 144) * NTAB)      // T then P' in ws

// ---------------------------------------------------------------------------
// R18: GEMM collapsed into T[4][400]/P'[144][400] table adds.
// R19: 1 wave/det pipelined pivot: 170us, but spills (WRITE 13.5MB scratch).
// R20: bigger reg budget: spills persist, 181us.
// R21: 2 waves/det: clean alloc but 198us (50 barriers/det).
// R22: rolled shift-loop: 50 PHIs re-spilled, 261us.
// R23: two-panel LU (25 live cols max): CLEAN (VGPR 40, WRITE=output only,
//      no barriers) yet still 181us @ VALUBusy 86%. Measured issue cycles
//      ~23.4K/wave vs ~8K static @2cyc -> the ~2700 cross-lane ops/wave
//      (readlane/DPP) must cost ~6-8 cyc each. VALU-pipe-bound on
//      broadcasts, not on math.
// R24: move phase-2's 625 broadcasts (of 1225 total) from readlane (VALU
//      pipe) to ds_bpermute (LDS pipe, parallel issue, no LDS storage).
//      Balances the two pipes at f~0.5. Bit-exact: bpermute reads the
//      same pre-update value, same fma.
// R25 (this round): R24 bench died to a container infra failure (no
//      compile error / no absmax verdict). Code path audited: bpermute is
//      convergent, no new sync, no hang vector. Resubmitting unchanged
//      to get the measurement.
// ---------------------------------------------------------------------------

// Wave64 max-reduction via DPP (VALU-only). Lane 63 ends with global max.
__device__ __forceinline__ unsigned dpp_max64_to_lane63(unsigned x) {
  unsigned t;
  t = (unsigned)__builtin_amdgcn_update_dpp((int)x, (int)x, 0x111, 0xf, 0xf, false);
  x = x > t ? x : t;
  t = (unsigned)__builtin_amdgcn_update_dpp((int)x, (int)x, 0x112, 0xf, 0xf, false);
  x = x > t ? x : t;
  t = (unsigned)__builtin_amdgcn_update_dpp((int)x, (int)x, 0x114, 0xf, 0xf, false);
  x = x > t ? x : t;
  t = (unsigned)__builtin_amdgcn_update_dpp((int)x, (int)x, 0x118, 0xf, 0xf, false);
  x = x > t ? x : t;
  t = (unsigned)__builtin_amdgcn_update_dpp((int)x, (int)x, 0x142, 0xa, 0xf, false);
  x = x > t ? x : t;
  t = (unsigned)__builtin_amdgcn_update_dpp((int)x, (int)x, 0x143, 0xc, 0xf, false);
  x = x > t ? x : t;
  return x;
}

// 25-wide repeat
#define REPC(X) X(0) X(1) X(2) X(3) X(4) X(5) X(6) X(7) X(8) X(9) \
  X(10) X(11) X(12) X(13) X(14) X(15) X(16) X(17) X(18) X(19) \
  X(20) X(21) X(22) X(23) X(24)

// ---- Precompute: T[c][j] = tok[c].W_j ; P'[s][j] = pos[s].W_j + b_j ------
__global__ __launch_bounds__(256) void tp_kernel(
    const float* __restrict__ tok, const float* __restrict__ pos,
    const float* __restrict__ W,   const float* __restrict__ bvec,
    float* __restrict__ T, float* __restrict__ P)
{
  const int gid = blockIdx.x * 256 + threadIdx.x;
  if (gid >= 148 * NTAB) return;
  const int row = gid / NTAB;
  const int col = gid - row * NTAB;
  const float4* h4 = (const float4*)((row < 4) ? (tok + (size_t)row * DIM)
                                               : (pos + (size_t)(row - 4) * DIM));
  const float4* w4 = (const float4*)(W + (size_t)col * DIM);
  float acc = 0.0f;
  #pragma unroll
  for (int i = 0; i < DIM / 4; ++i) {
    float4 a = h4[i], b = w4[i];
    acc = fmaf(a.x, b.x, acc);
    acc = fmaf(a.y, b.y, acc);
    acc = fmaf(a.z, b.z, acc);
    acc = fmaf(a.w, b.w, acc);
  }
  if (row < 4) T[(size_t)row * NTAB + col] = acc;
  else         P[(size_t)(row - 4) * NTAB + col] = acc + bvec[col];
}

// One block per (batch, spin). Wave w handles determinant k=w.
// Lane r owns row r of phi. Two-panel LU; see header comment.
__global__ __launch_bounds__(256)
__attribute__((amdgpu_waves_per_eu(6)))
void det_kernel(
    const int*   __restrict__ configs,   // (B,100) int32
    const float* __restrict__ T,         // (4,400)
    const float* __restrict__ P,         // (144,400)  includes bias
    double*      __restrict__ dets)      // (B,2,4,2)  {logdet, sign}
{
  const int b    = blockIdx.x;
  const int spin = blockIdx.y;

  __shared__ int cfg[NSITE];
  __shared__ int idx[NOCC];
  __shared__ unsigned long long omask[2];
  __shared__ float stash[4][25][64];     // per-wave multiplier stash

  const int tid = threadIdx.x;

  // ---- wave-parallel occupied-index build (ballot + prefix popcount) ----
  bool occv = false;
  if (tid < NSITE) {
    const int c = configs[(size_t)b * NSITE + tid];
    cfg[tid] = c;
    occv = (spin == 0) ? (c == 1 || c == 3) : (c == 2 || c == 3);
  }
  const unsigned long long bal = __ballot(occv);
  if ((tid & 63) == 0 && tid < 128) omask[tid >> 6] = bal;
  __syncthreads();
  if (tid < NSITE) {
    const unsigned long long m0 = omask[0], m1 = omask[1];
    const int mtot = __popcll(m0) + __popcll(m1);
    const int need = (mtot < NOCC) ? (NOCC - mtot) : 0;
    int pocc;
    if (tid >= 64) pocc = __popcll(m0) + __popcll(m1 & ((1ull << (tid - 64)) - 1ull));
    else           pocc = __popcll(m0 & ((1ull << tid) - 1ull));
    const int punocc = tid - pocc;
    const bool sel = occv ? (pocc < NOCC) : (punocc < need);
    const int  poscap = (pocc  < NOCC) ? pocc  : NOCC;
    const int  pfill  = (punocc < need) ? punocc : need;
    if (sel) idx[poscap + pfill] = tid;
  }
  __syncthreads();

  const int lane = tid & 63;
  const int wave = tid >> 6;
  const int wave_u  = __builtin_amdgcn_readfirstlane(wave);
  const int colbase = spin * 200 + wave_u * 50;          // uniform

  const bool act  = (lane < NOCC);
  const int  site = idx[act ? lane : 0];
  const int  cc0  = cfg[site];
  const float* Trow = T + (size_t)cc0  * NTAB + colbase;
  const float* Prow = P + (size_t)site * NTAB + colbase;
  // colbase multiple of 50 -> byte offset multiple of 200 -> 8-aligned
  const float2* T2 = (const float2*)Trow;
  const float2* P2 = (const float2*)Prow;

  // ================= phase 1: cols 0..24 in c0..c24 =================
  #define DECLC(i) float c##i;
  REPC(DECLC)
  #undef DECLC
  #define LQ(i0, i1) { float2 a = T2[(i0) / 2], d = P2[(i0) / 2]; \
      c##i0 = a.x + d.x; c##i1 = a.y + d.y; }
  LQ(0, 1)  LQ(2, 3)  LQ(4, 5)  LQ(6, 7)  LQ(8, 9)  LQ(10, 11)
  LQ(12, 13) LQ(14, 15) LQ(16, 17) LQ(18, 19) LQ(20, 21) LQ(22, 23)
  #undef LQ
  c24 = Trow[24] + Prow[24];
  #define ZC(i) c##i = act ? c##i : 0.0f;
  REPC(ZC)
  #undef ZC

  unsigned aliveq = act ? 0xFFFFFFFFu : 0u;   // per-lane alive mask
  float    mant_prod = 1.0f;                  // pivot mantissa product < 2^50
  int      esum = 0;
  unsigned sgnx = 0u;
  unsigned long long chosen = 0ull;
  int      invsum = 0;
  const unsigned lu = (unsigned)lane;
  unsigned long long pp[3] = {0ull, 0ull, 0ull};  // packed pivot lanes, 6b ea

  // update chains, c family: UCF_N applies UC to regs N..24
  #define UC(L) { const float pc = __int_as_float( \
      __builtin_amdgcn_readlane(__float_as_int(c##L), p)); \
      c##L = fmaf(-mult, pc, c##L); }
  #define UCF_25
  #define UCF_24 UC(24)
  #define UCF_23 UC(23) UCF_24
  #define UCF_22 UC(22) UCF_23
  #define UCF_21 UC(21) UCF_22
  #define UCF_20 UC(20) UCF_21
  #define UCF_19 UC(19) UCF_20
  #define UCF_18 UC(18) UCF_19
  #define UCF_17 UC(17) UCF_18
  #define UCF_16 UC(16) UCF_17
  #define UCF_15 UC(15) UCF_16
  #define UCF_14 UC(14) UCF_15
  #define UCF_13 UC(13) UCF_14
  #define UCF_12 UC(12) UCF_13
  #define UCF_11 UC(11) UCF_12
  #define UCF_10 UC(10) UCF_11
  #define UCF_9  UC(9)  UCF_10
  #define UCF_8  UC(8)  UCF_9
  #define UCF_7  UC(7)  UCF_8
  #define UCF_6  UC(6)  UCF_7
  #define UCF_5  UC(5)  UCF_6
  #define UCF_4  UC(4)  UCF_5
  #define UCF_3  UC(3)  UCF_4
  #define UCF_2  UC(2)  UCF_3
  #define UCF_1  UC(1)  UCF_2

  // Step J (global step J, 0..24): pivot, account, stash mult, update tail.
  #define P1STEP(J, N) { \
    unsigned key = ((__float_as_uint(c##J) & 0x7FFFFFC0u) | lu) & aliveq; \
    key = dpp_max64_to_lane63(key); \
    const int p = __builtin_amdgcn_readlane((int)key, 63) & 63; \
    const unsigned pb = (unsigned)__builtin_amdgcn_readlane( \
        __float_as_int(c##J), p); \
    esum += (int)((pb >> 23) & 0xFFu) - 127; \
    sgnx ^= (pb & 0x80000000u); \
    mant_prod *= __uint_as_float((pb & 0x007FFFFFu) | 0x3F800000u); \
    invsum += __popcll(chosen >> (p + 1)); \
    chosen |= 1ull << (unsigned)p; \
    aliveq = (lane == p) ? 0u : aliveq; \
    pp[(J) / 10] |= ((unsigned long long)(unsigned)p) << (6 * ((J) % 10)); \
    const float piv = __uint_as_float(pb); \
    float r0 = __builtin_amdgcn_rcpf(piv); \
    r0 = fmaf(fmaf(-piv, r0, 1.0f), r0, r0); \
    const float rp = ((pb & 0x7FFFFFFFu) != 0u) ? r0 : 0.0f; \
    const float mult = __uint_as_float(__float_as_uint(c##J * rp) & aliveq); \
    stash[wave_u][(J)][lane] = mult; \
    UCF_##N \
  }

  P1STEP(0,1)   P1STEP(1,2)   P1STEP(2,3)   P1STEP(3,4)   P1STEP(4,5)
  P1STEP(5,6)   P1STEP(6,7)   P1STEP(7,8)   P1STEP(8,9)   P1STEP(9,10)
  P1STEP(10,11) P1STEP(11,12) P1STEP(12,13) P1STEP(13,14) P1STEP(14,15)
  P1STEP(15,16) P1STEP(16,17) P1STEP(17,18) P1STEP(18,19) P1STEP(19,20)
  P1STEP(20,21) P1STEP(21,22) P1STEP(22,23) P1STEP(23,24) P1STEP(24,25)
  #undef P1STEP

  // ================= phase 2: cols 25..49, replay steps 0..24 ============
  // Broadcasts ride the LDS pipe (ds_bpermute, no LDS storage) so the
  // saturated VALU pipe only executes the fmas. Bit-exact vs readlane.
  #define DECLT(i) float t##i;
  REPC(DECLT)
  #undef DECLT
  #define LT(i) t##i = Trow[25 + (i)] + Prow[25 + (i)];
  REPC(LT)
  #undef LT
  #define ZT(i) t##i = act ? t##i : 0.0f;
  REPC(ZT)
  #undef ZT

  // bpermute update: pc pulled from lane (pa>>2) through LDS crossbar
  #define BT(L) { const float pc = __int_as_float( \
      __builtin_amdgcn_ds_bpermute(pa, __float_as_int(t##L))); \
      t##L = fmaf(-mult, pc, t##L); }

  // replay step J on all 25 trailing cols (mult from stash, p from pack);
  // sched_barrier every 6 bounds in-flight bpermute results (reg pressure)
  #define P2J(J) { \
    const int pa = ((int)((pp[(J) / 10] >> (6 * ((J) % 10))) & 63ull)) << 2; \
    const float mult = stash[wave_u][(J)][lane]; \
    BT(0)  BT(1)  BT(2)  BT(3)  BT(4)  BT(5) \
    __builtin_amdgcn_sched_barrier(0); \
    BT(6)  BT(7)  BT(8)  BT(9)  BT(10) BT(11) \
    __builtin_amdgcn_sched_barrier(0); \
    BT(12) BT(13) BT(14) BT(15) BT(16) BT(17) \
    __builtin_amdgcn_sched_barrier(0); \
    BT(18) BT(19) BT(20) BT(21) BT(22) BT(23) BT(24) \
    __builtin_amdgcn_sched_barrier(0); \
  }
  P2J(0)  P2J(1)  P2J(2)  P2J(3)  P2J(4)  P2J(5)  P2J(6)  P2J(7)
  P2J(8)  P2J(9)  P2J(10) P2J(11) P2J(12) P2J(13) P2J(14) P2J(15)
  P2J(16) P2J(17) P2J(18) P2J(19) P2J(20) P2J(21) P2J(22) P2J(23)
  P2J(24)
  #undef P2J
  #undef BT

  // ================= phase 3: factor steps 25..49 on t0..t24 =============
  #define UT(L) { const float pc = __int_as_float( \
      __builtin_amdgcn_readlane(__float_as_int(t##L), p)); \
      t##L = fmaf(-mult, pc, t##L); }
  #define UTF_25
  #define UTF_24 UT(24)
  #define UTF_23 UT(23) UTF_24
  #define UTF_22 UT(22) UTF_23
  #define UTF_21 UT(21) UTF_22
  #define UTF_20 UT(20) UTF_21
  #define UTF_19 UT(19) UTF_20
  #define UTF_18 UT(18) UTF_19
  #define UTF_17 UT(17) UTF_18
  #define UTF_16 UT(16) UTF_17
  #define UTF_15 UT(15) UTF_16
  #define UTF_14 UT(14) UTF_15
  #define UTF_13 UT(13) UTF_14
  #define UTF_12 UT(12) UTF_13
  #define UTF_11 UT(11) UTF_12
  #define UTF_10 UT(10) UTF_11
  #define UTF_9  UT(9)  UTF_10
  #define UTF_8  UT(8)  UTF_9
  #define UTF_7  UT(7)  UTF_8
  #define UTF_6  UT(6)  UTF_7
  #define UTF_5  UT(5)  UTF_6
  #define UTF_4  UT(4)  UTF_5
  #define UTF_3  UT(3)  UTF_4
  #define UTF_2  UT(2)  UTF_3
  #define UTF_1  UT(1)  UTF_2

  #define P3STEP(L, N) { \
    unsigned key = ((__float_as_uint(t##L) & 0x7FFFFFC0u) | lu) & aliveq; \
    key = dpp_max64_to_lane63(key); \
    const int p = __builtin_amdgcn_readlane((int)key, 63) & 63; \
    const unsigned pb = (unsigned)__builtin_amdgcn_readlane( \
        __float_as_int(t##L), p); \
    esum += (int)((pb >> 23) & 0xFFu) - 127; \
    sgnx ^= (pb & 0x80000000u); \
    mant_prod *= __uint_as_float((pb & 0x007FFFFFu) | 0x3F800000u); \
    invsum += __popcll(chosen >> (p + 1)); \
    chosen |= 1ull << (unsigned)p; \
    aliveq = (lane == p) ? 0u : aliveq; \
    const float piv = __uint_as_float(pb); \
    float r0 = __builtin_amdgcn_rcpf(piv); \
    r0 = fmaf(fmaf(-piv, r0, 1.0f), r0, r0); \
    const float rp = ((pb & 0x7FFFFFFFu) != 0u) ? r0 : 0.0f; \
    const float mult = __uint_as_float(__float_as_uint(t##L * rp) & aliveq); \
    UTF_##N \
  }

  P3STEP(0,1)   P3STEP(1,2)   P3STEP(2,3)   P3STEP(3,4)   P3STEP(4,5)
  P3STEP(5,6)   P3STEP(6,7)   P3STEP(7,8)   P3STEP(8,9)   P3STEP(9,10)
  P3STEP(10,11) P3STEP(11,12) P3STEP(12,13) P3STEP(13,14) P3STEP(14,15)
  P3STEP(15,16) P3STEP(16,17) P3STEP(17,18) P3STEP(18,19) P3STEP(19,20)
  P3STEP(20,21) P3STEP(21,22) P3STEP(22,23) P3STEP(23,24) P3STEP(24,25)
  #undef P3STEP
  #undef UT
  #undef UC

  const double logdet =
      log((double)mant_prod) + (double)esum * 0.6931471805599453;
  const int sgn = (((sgnx >> 31) + (unsigned)invsum) & 1u) ? -1 : 1;

  if (lane == 0) {
    size_t o = (((size_t)b * 2 + spin) * KDET + wave) * 2;
    dets[o]     = logdet;
    dets[o + 1] = (double)sgn;
  }
}

// PLANAR complex64 output: out[0..B) = log_abs (real), out[B..2B) = phase (imag)
__global__ __launch_bounds__(256) void combine_kernel(
    const double* __restrict__ dets, float* __restrict__ out, int B)
{
  int b = blockIdx.x * blockDim.x + threadIdx.x;
  if (b >= B) return;
  const double* du = dets + ((size_t)b * 2 + 0) * KDET * 2;
  const double* dd = dets + ((size_t)b * 2 + 1) * KDET * 2;
  double t[KDET], s[KDET], m = -1e300;
  #pragma unroll
  for (int k = 0; k < KDET; ++k) {
    t[k] = du[2 * k] + dd[2 * k];
    s[k] = du[2 * k + 1] * dd[2 * k + 1];
    if (t[k] > m) m = t[k];
  }
  double sum = 0.0;
  #pragma unroll
  for (int k = 0; k < KDET; ++k) {
    if (t[k] > -1e290) sum += s[k] * exp(t[k] - m);
  }
  double p  = (m > -1e290) ? exp(m) * fabs(sum) : 0.0;
  double la = log(p + 1e-30);                    // reproduce ref clamp exactly
  float phase = (sum >= 0.0) ? 0.0f : 3.14159265358979f;
  out[b]     = (float)la;
  out[B + b] = phase;
}

extern "C" void kernel_launch(void* const* d_in, const int* in_sizes, int n_in,
                              void* d_out, int out_size, void* d_ws, size_t ws_size,
                              hipStream_t stream) {
  const int*   configs = (const int*)  d_in[0];
  const float* tok     = (const float*)d_in[1];
  const float* pos     = (const float*)d_in[2];
  const float* W       = (const float*)d_in[3];
  const float* bv      = (const float*)d_in[4];

  float*  wsf  = (float*)d_ws;
  float*  T    = wsf;                       // 4*400 floats
  float*  P    = wsf + 4 * NTAB;            // 144*400 floats
  double* dets = (double*)(wsf + TP_FLOATS);  // 236800B offset, 8-aligned
  const int B = in_sizes[0] / NSITE;        // total ws: ~499KB

  tp_kernel<<<(148 * NTAB + 255) / 256, 256, 0, stream>>>(tok, pos, W, bv, T, P);
  dim3 grid(B, 2);
  det_kernel<<<grid, 256, 0, stream>>>(configs, T, P, dets);
  combine_kernel<<<(B + 255) / 256, 256, 0, stream>>>(dets, (float*)d_out, B);
}